// Round 14
// baseline (1785.239 us; speedup 1.0000x reference)
//
#include <hip/hip_runtime.h>

#define F 4096          // feature dim (S_DIM == HID == A_DIM)
#define NE 44
#define NN 14
#define KB 16           // k-split factor
#define KC 256          // k-chunk width per block
#define KT 32           // k per tile (tile = 256 rows x 32 k x 4B = 32 KB)
#define NT 8            // tiles per block (KC/KT)
#define BUF 3           // LDS tile ring depth
#define YPART 57344     // 14*4096, one partial Y buffer
#define H1SZ 180224     // 44*4096

// deterministic edge list from reference _edge_list()
__device__ constexpr int SRC[NE] = {
    0,1,2,3,4,5,6,7,8,9,10,11,12,13,          // fwd ring
    1,2,3,4,5,6,7,8,9,10,11,12,13,0,          // rev ring
    0,1,2,3,4,5,6,7,8,9,10,11,12,13,          // skip-2 ring
    0,7};
__device__ constexpr int DST[NE] = {
    1,2,3,4,5,6,7,8,9,10,11,12,13,0,
    0,1,2,3,4,5,6,7,8,9,10,11,12,13,
    2,3,4,5,6,7,8,9,10,11,12,13,0,1,
    7,0};
// deg: 3 everywhere except nodes 0 and 7 (4)
__device__ constexpr float INVDEG[NN] = {
    0.25f, 1.f/3.f, 1.f/3.f, 1.f/3.f, 1.f/3.f, 1.f/3.f, 1.f/3.f,
    0.25f, 1.f/3.f, 1.f/3.f, 1.f/3.f, 1.f/3.f, 1.f/3.f, 1.f/3.f};

// async global->LDS, 16 B per lane; LDS dest = uniform base + lane*16 (linear)
__device__ __forceinline__ void gload16(const float* g, float* l) {
    __builtin_amdgcn_global_load_lds(
        (const __attribute__((address_space(1))) void*)g,
        (__attribute__((address_space(3))) void*)l, 16, 0, 0);
}

// ---------------- prep: A = node2(edge_features) -------------------------
__global__ __launch_bounds__(256) void prep_x_k(const float* __restrict__ x,
                                                float* __restrict__ Aout) {
    int f = blockIdx.x * 256 + threadIdx.x;   // 16 blocks cover 4096
    float s[NN];
#pragma unroll
    for (int n = 0; n < NN; ++n) s[n] = 0.f;
#pragma unroll
    for (int e = 0; e < NE; ++e) s[DST[e]] += x[e * F + f];
    float node[NN];
#pragma unroll
    for (int n = 0; n < NN; ++n) node[n] = s[n] * INVDEG[n];
    float n2[NN];
#pragma unroll
    for (int n = 0; n < NN; ++n) n2[n] = 0.f;
#pragma unroll
    for (int e = 0; e < NE; ++e) n2[DST[e]] += node[SRC[e]];
#pragma unroll
    for (int m = 0; m < NN; ++m) Aout[m * F + f] = n2[m];
}

// inner layers: edge feat = leaky_relu(0.5*(Y[src]+Y[dst]) + b), Y = sum of KB partials
__device__ __forceinline__ void prep_col(const float* __restrict__ Yp,
                                         const float* __restrict__ b,
                                         float* __restrict__ Aout, int f) {
    float y[NN];
#pragma unroll
    for (int m = 0; m < NN; ++m) {
        float s = 0.f;
#pragma unroll
        for (int kb = 0; kb < KB; ++kb) s += Yp[kb * YPART + m * F + f];
        y[m] = s;
    }
    float bias = b[f];
    float s[NN];
#pragma unroll
    for (int n = 0; n < NN; ++n) s[n] = 0.f;
#pragma unroll
    for (int e = 0; e < NE; ++e) {
        float eh = 0.5f * (y[SRC[e]] + y[DST[e]]) + bias;
        eh = eh > 0.f ? eh : 0.01f * eh;      // leaky_relu(0.01)
        s[DST[e]] += eh;
    }
    float node[NN];
#pragma unroll
    for (int n = 0; n < NN; ++n) node[n] = s[n] * INVDEG[n];
    float n2[NN];
#pragma unroll
    for (int n = 0; n < NN; ++n) n2[n] = 0.f;
#pragma unroll
    for (int e = 0; e < NE; ++e) n2[DST[e]] += node[SRC[e]];
#pragma unroll
    for (int m = 0; m < NN; ++m) Aout[m * F + f] = n2[m];
}

__global__ __launch_bounds__(256) void prep2_k(const float* __restrict__ Yp1,
                                               const float* __restrict__ b1,
                                               float* __restrict__ A1,
                                               const float* __restrict__ Yp2,
                                               const float* __restrict__ b2,
                                               float* __restrict__ A2) {
    int bx = blockIdx.x;
    if (bx < 16) {
        prep_col(Yp1, b1, A1, bx * 256 + threadIdx.x);
    } else {
        prep_col(Yp2, b2, A2, (bx - 16) * 256 + threadIdx.x);
    }
}

// ---------------- GEMM: Y[m][n] = sum_k A[m][k] * W[n][k] ----------------
// R13 tile/swizzle + T3+T4 schedule: raw s_barrier + counted vmcnt so the
// next tiles' global_load_lds stay IN FLIGHT across barriers (never drain
// to 0 mid-loop). BUF=3 ring of 32 KB tiles, depth-2 prefetch: 64 KB/CU
// continuously queued in the memory system.
// Per iter: vmcnt(8) [tile t landed; t+1 still flying] -> sched_barrier ->
// s_barrier [all waves past compute(t-1)] -> stage(t+2) into buf[(t+2)%3]
// (safe: == buf[(t-1)%3], readers done) -> compute(t).
// Lane == W row (256 rows/block), acc[14], no cross-lane reduction.
// LDS 110 KB -> 1 block/CU. Per branch: 16 nb x 16 kb = 256 blocks.
__global__ __launch_bounds__(256, 1) void gemm2_k(const float* __restrict__ A1,
                                                  const float* __restrict__ W1,
                                                  float* __restrict__ Y1,
                                                  const float* __restrict__ A2,
                                                  const float* __restrict__ W2,
                                                  float* __restrict__ Y2,
                                                  int half) {
    __shared__ float Alds[NN * KC];          // 14336 B
    __shared__ float Wlds[BUF][2048 * 4];    // 3 x 32768 B (total 112640 B)
    int bx = blockIdx.x;
    const float* A = A1; const float* W = W1; float* Y = Y1;
    if (bx >= half) { A = A2; W = W2; Y = Y2; bx -= half; }
    const int kb = bx & (KB - 1);     // k chunk (256 wide)
    const int nb = bx >> 4;           // 16 row-blocks of 256
    const int tid = threadIdx.x;      // == row within block
    const int k0  = kb * KC;
    const int brow0 = nb * 256;

    // ---- prologue: stage A chunk + tiles 0,1 (all async) ----
#pragma unroll
    for (int i = 0; i < 4; ++i) {
        int p = i * 256 + tid;
        if (p < 896)
            gload16(A + (p >> 6) * F + k0 + (p & 63) * 4, &Alds[p * 4]);
    }
#pragma unroll
    for (int tt = 0; tt < 2; ++tt) {
#pragma unroll
        for (int i = 0; i < 8; ++i) {
            int p = i * 256 + tid;             // granule: row p>>3, slot p&7
            gload16(W + (size_t)(brow0 + (p >> 3)) * F + k0 + tt * KT
                      + (((p & 7) ^ ((p >> 3) & 7)) * 4),
                    &Wlds[tt][p * 4]);
        }
    }

    float acc[NN];
#pragma unroll
    for (int m = 0; m < NN; ++m) acc[m] = 0.f;

    const int rsw = tid & 7;               // row&7 for read-side swizzle

#pragma unroll
    for (int t = 0; t < NT; ++t) {
        // tile t landed when <= 8 newest (tile t+1) remain outstanding
        if (t < NT - 1)
            asm volatile("s_waitcnt vmcnt(8)" ::: "memory");
        else
            asm volatile("s_waitcnt vmcnt(0)" ::: "memory");
        __builtin_amdgcn_sched_barrier(0);
        __builtin_amdgcn_s_barrier();          // raw: no implicit drain
        if (t + 2 < NT) {                      // stage tile t+2 (async)
            const int kofs = k0 + (t + 2) * KT;
            float* dst = &Wlds[(t + 2) % BUF][0];
#pragma unroll
            for (int i = 0; i < 8; ++i) {
                int p = i * 256 + tid;
                gload16(W + (size_t)(brow0 + (p >> 3)) * F + kofs
                          + (((p & 7) ^ ((p >> 3) & 7)) * 4),
                        &dst[p * 4]);
            }
        }
        // compute tile t: 8 ksteps, lane owns row tid
        const float* wbuf = &Wlds[t % BUF][0];
#pragma unroll
        for (int ks = 0; ks < 8; ++ks) {
            float4 wq = *(const float4*)&wbuf[(tid * 8 + (ks ^ rsw)) * 4];
#pragma unroll
            for (int m = 0; m < NN; ++m) {
                float4 aq = *(const float4*)&Alds[m * KC + t * KT + ks * 4];
                acc[m] += wq.x * aq.x + wq.y * aq.y + wq.z * aq.z + wq.w * aq.w;
            }
        }
    }

    // coalesced stores: per m, 256 threads -> 256 consecutive rows
#pragma unroll
    for (int m = 0; m < NN; ++m)
        Y[kb * YPART + m * F + brow0 + tid] = acc[m];
}

// ---------------- final: h1 edge expansion + h2 tiny GEMV ----------------
__global__ __launch_bounds__(256) void final_k(const float* __restrict__ Ypa5,
                                               const float* __restrict__ ba5,
                                               const float* __restrict__ Av2,
                                               const float* __restrict__ Wv5,
                                               const float* __restrict__ bv5,
                                               float* __restrict__ out) {
    __shared__ float red[NN][257];
    if (blockIdx.x < 176) {
        int idx4 = (blockIdx.x * 256 + threadIdx.x) * 4;  // 44*4096 elements
        int e = idx4 >> 12, f = idx4 & 4095;
        int se = SRC[e], de = DST[e];
        float4 ys = make_float4(0.f, 0.f, 0.f, 0.f);
        float4 yd = make_float4(0.f, 0.f, 0.f, 0.f);
#pragma unroll
        for (int kb = 0; kb < KB; ++kb) {
            float4 s = *(const float4*)(Ypa5 + kb * YPART + se * F + f);
            float4 d = *(const float4*)(Ypa5 + kb * YPART + de * F + f);
            ys.x += s.x; ys.y += s.y; ys.z += s.z; ys.w += s.w;
            yd.x += d.x; yd.y += d.y; yd.z += d.z; yd.w += d.w;
        }
        float4 bb = *(const float4*)(ba5 + f);
        float4 o;
        o.x = 0.5f * (ys.x + yd.x) + bb.x;
        o.y = 0.5f * (ys.y + yd.y) + bb.y;
        o.z = 0.5f * (ys.z + yd.z) + bb.z;
        o.w = 0.5f * (ys.w + yd.w) + bb.w;
        *(float4*)(out + idx4) = o;
    } else {
        // y[n] = dot(Av2[n], Wv5); h2[e] = 0.5*(y[src]+y[dst]) + bv5
        int t = threadIdx.x;
        float acc[NN];
#pragma unroll
        for (int m = 0; m < NN; ++m) acc[m] = 0.f;
        for (int f = t; f < F; f += 256) {
            float wv = Wv5[f];
#pragma unroll
            for (int m = 0; m < NN; ++m) acc[m] += Av2[m * F + f] * wv;
        }
#pragma unroll
        for (int m = 0; m < NN; ++m) red[m][t] = acc[m];
        __syncthreads();
        for (int s = 128; s > 0; s >>= 1) {
            if (t < s) {
#pragma unroll
                for (int m = 0; m < NN; ++m) red[m][t] += red[m][t + s];
            }
            __syncthreads();
        }
        if (t < NE) {
            float ys = red[SRC[t]][0], yd = red[DST[t]][0];
            out[H1SZ + t] = 0.5f * (ys + yd) + bv5[0];
        }
    }
}

extern "C" void kernel_launch(void* const* d_in, const int* in_sizes, int n_in,
                              void* d_out, int out_size, void* d_ws, size_t ws_size,
                              hipStream_t stream) {
    const float* x   = (const float*)d_in[0];
    const float* Wa1 = (const float*)d_in[3];
    const float* ba1 = (const float*)d_in[4];
    const float* Wa2 = (const float*)d_in[5];
    const float* ba2 = (const float*)d_in[6];
    const float* Wa5 = (const float*)d_in[7];
    const float* ba5 = (const float*)d_in[8];
    const float* Wv1 = (const float*)d_in[9];
    const float* bv1 = (const float*)d_in[10];
    const float* Wv2 = (const float*)d_in[11];
    const float* bv2 = (const float*)d_in[12];
    const float* Wv5 = (const float*)d_in[13];
    const float* bv5 = (const float*)d_in[14];
    float* out = (float*)d_out;

    float* ws  = (float*)d_ws;
    float* Ax  = ws;                   // 57344
    float* Aa  = ws + 57344;           // 57344
    float* Av  = ws + 114688;          // 57344
    float* Ypa = ws + 172032;          // KB*57344 = 917504
    float* Ypv = ws + 1089536;         // KB*57344 = 917504 (total ~8.03 MB)

    prep_x_k<<<16,  256, 0, stream>>>(x, Ax);
    gemm2_k <<<512, 256, 0, stream>>>(Ax, Wa1, Ypa, Ax, Wv1, Ypv, 256);
    prep2_k <<<32,  256, 0, stream>>>(Ypa, ba1, Aa, Ypv, bv1, Av);
    gemm2_k <<<512, 256, 0, stream>>>(Aa, Wa2, Ypa, Av, Wv2, Ypv, 256);
    prep2_k <<<32,  256, 0, stream>>>(Ypa, ba2, Aa, Ypv, bv2, Av);
    gemm2_k <<<256, 256, 0, stream>>>(Aa, Wa5, Ypa, Aa, Wa5, Ypa, 256);
    final_k <<<177, 256, 0, stream>>>(Ypa, ba5, Av, Wv5, bv5, out);
}

// Round 15
// 129.677 us; speedup vs baseline: 13.7668x; 13.7668x over previous
//
#include <hip/hip_runtime.h>

#define F 4096          // feature dim (S_DIM == HID == A_DIM)
#define NE 44
#define NN 14
#define KB 16           // k-split factor
#define KC 256          // k-chunk width per block
#define NKS 16          // ksteps per chunk (KC/16)
#define YPART 57344     // 14*4096, one partial Y buffer
#define H1SZ 180224     // 44*4096

// deterministic edge list from reference _edge_list()
__device__ constexpr int SRC[NE] = {
    0,1,2,3,4,5,6,7,8,9,10,11,12,13,          // fwd ring
    1,2,3,4,5,6,7,8,9,10,11,12,13,0,          // rev ring
    0,1,2,3,4,5,6,7,8,9,10,11,12,13,          // skip-2 ring
    0,7};
__device__ constexpr int DST[NE] = {
    1,2,3,4,5,6,7,8,9,10,11,12,13,0,
    0,1,2,3,4,5,6,7,8,9,10,11,12,13,
    2,3,4,5,6,7,8,9,10,11,12,13,0,1,
    7,0};
// deg: 3 everywhere except nodes 0 and 7 (4)
__device__ constexpr float INVDEG[NN] = {
    0.25f, 1.f/3.f, 1.f/3.f, 1.f/3.f, 1.f/3.f, 1.f/3.f, 1.f/3.f,
    0.25f, 1.f/3.f, 1.f/3.f, 1.f/3.f, 1.f/3.f, 1.f/3.f, 1.f/3.f};

// async global->LDS, 16 B per lane; LDS dest = uniform base + lane*16 (linear)
__device__ __forceinline__ void gload16(const float* g, float* l) {
    __builtin_amdgcn_global_load_lds(
        (const __attribute__((address_space(1))) void*)g,
        (__attribute__((address_space(3))) void*)l, 16, 0, 0);
}

// ---------------- prep: A = node2(edge_features) -------------------------
__global__ __launch_bounds__(256) void prep_x_k(const float* __restrict__ x,
                                                float* __restrict__ Aout) {
    int f = blockIdx.x * 256 + threadIdx.x;   // 16 blocks cover 4096
    float s[NN];
#pragma unroll
    for (int n = 0; n < NN; ++n) s[n] = 0.f;
#pragma unroll
    for (int e = 0; e < NE; ++e) s[DST[e]] += x[e * F + f];
    float node[NN];
#pragma unroll
    for (int n = 0; n < NN; ++n) node[n] = s[n] * INVDEG[n];
    float n2[NN];
#pragma unroll
    for (int n = 0; n < NN; ++n) n2[n] = 0.f;
#pragma unroll
    for (int e = 0; e < NE; ++e) n2[DST[e]] += node[SRC[e]];
#pragma unroll
    for (int m = 0; m < NN; ++m) Aout[m * F + f] = n2[m];
}

// inner layers: edge feat = leaky_relu(0.5*(Y[src]+Y[dst]) + b), Y = sum of KB partials
__device__ __forceinline__ void prep_col(const float* __restrict__ Yp,
                                         const float* __restrict__ b,
                                         float* __restrict__ Aout, int f) {
    float y[NN];
#pragma unroll
    for (int m = 0; m < NN; ++m) {
        float s = 0.f;
#pragma unroll
        for (int kb = 0; kb < KB; ++kb) s += Yp[kb * YPART + m * F + f];
        y[m] = s;
    }
    float bias = b[f];
    float s[NN];
#pragma unroll
    for (int n = 0; n < NN; ++n) s[n] = 0.f;
#pragma unroll
    for (int e = 0; e < NE; ++e) {
        float eh = 0.5f * (y[SRC[e]] + y[DST[e]]) + bias;
        eh = eh > 0.f ? eh : 0.01f * eh;      // leaky_relu(0.01)
        s[DST[e]] += eh;
    }
    float node[NN];
#pragma unroll
    for (int n = 0; n < NN; ++n) node[n] = s[n] * INVDEG[n];
    float n2[NN];
#pragma unroll
    for (int n = 0; n < NN; ++n) n2[n] = 0.f;
#pragma unroll
    for (int e = 0; e < NE; ++e) n2[DST[e]] += node[SRC[e]];
#pragma unroll
    for (int m = 0; m < NN; ++m) Aout[m * F + f] = n2[m];
}

__global__ __launch_bounds__(256) void prep2_k(const float* __restrict__ Yp1,
                                               const float* __restrict__ b1,
                                               float* __restrict__ A1,
                                               const float* __restrict__ Yp2,
                                               const float* __restrict__ b2,
                                               float* __restrict__ A2) {
    int bx = blockIdx.x;
    if (bx < 16) {
        prep_col(Yp1, b1, A1, bx * 256 + threadIdx.x);
    } else {
        prep_col(Yp2, b2, A2, (bx - 16) * 256 + threadIdx.x);
    }
}

// ---------------- GEMM: Y[m][n] = sum_k A[m][k] * W[n][k] ----------------
// R7 structure (proven best) with the OCCUPANCY lever: KC 512->256 shrinks
// the A-LDS chunk to 14 KB so 8 blocks/CU fit -> 32 waves/CU (8/SIMD).
// Issue-rate math: per kstep a wave issues ~112 cy (14 ds_read + 56 FMA);
// 7 sibling waves x 112 ~= 784 cy covers the ~900 cy W-load latency that
// the compiler's depth-2 schedule exposes. launch_bounds(256,8) caps VGPR
// at 64 (R7 measured 44). Lane = (row l>>2, k-quarter l&3); acc[14];
// 2-level butterfly. Per branch: 64 nb x 16 kb = 1024 blocks; fused 2048.
__global__ __launch_bounds__(256, 8) void gemm2_k(const float* __restrict__ A1,
                                                  const float* __restrict__ W1,
                                                  float* __restrict__ Y1,
                                                  const float* __restrict__ A2,
                                                  const float* __restrict__ W2,
                                                  float* __restrict__ Y2,
                                                  int half) {
    __shared__ float Alds[NN * KC];   // 14336 B -> 8 blocks/CU
    int bx = blockIdx.x;
    const float* A = A1; const float* W = W1; float* Y = Y1;
    if (bx >= half) { A = A2; W = W2; Y = Y2; bx -= half; }
    const int kb = bx & (KB - 1);   // k chunk (256 wide)
    const int nb = bx >> 4;         // 64 row-groups of 64
    const int tid = threadIdx.x;
    const int w   = tid >> 6;
    const int l   = tid & 63;
    const int row = nb * 64 + w * 16 + (l >> 2);  // this lane's W row
    const int kq4 = (l & 3) * 4;                  // k quarter offset
    const int k0  = kb * KC;

    // stage A chunk: 14*KC floats = 896 float4 (3.5 x 256 threads)
#pragma unroll
    for (int i = 0; i < 4; ++i) {
        int p = i * 256 + tid;            // float4 index
        if (p < 896)
            gload16(A + (p >> 6) * F + k0 + (p & 63) * 4, &Alds[p * 4]);
    }
    __syncthreads();

    const float* Wrow = W + (size_t)row * F + k0 + kq4;

    float acc[NN];
#pragma unroll
    for (int m = 0; m < NN; ++m) acc[m] = 0.f;

#pragma unroll 4
    for (int ks = 0; ks < NKS; ++ks) {
        float4 wv = *(const float4*)(Wrow + ks * 16);
        const float* al = &Alds[ks * 16 + kq4];
#pragma unroll
        for (int m = 0; m < NN; ++m) {
            float4 a = *(const float4*)(al + m * KC);
            acc[m] += wv.x * a.x + wv.y * a.y + wv.z * a.z + wv.w * a.w;
        }
    }

    // 2-level butterfly over the 4 k-lanes of this row
#pragma unroll
    for (int m = 0; m < NN; ++m) {
        float v = acc[m];
        v += __shfl_xor(v, 1);
        v += __shfl_xor(v, 2);
        acc[m] = v;
    }
    if ((l & 3) == 0) {
#pragma unroll
        for (int m = 0; m < NN; ++m)
            Y[kb * YPART + m * F + row] = acc[m];
    }
}

// ---------------- final: h1 edge expansion + h2 tiny GEMV ----------------
__global__ __launch_bounds__(256) void final_k(const float* __restrict__ Ypa5,
                                               const float* __restrict__ ba5,
                                               const float* __restrict__ Av2,
                                               const float* __restrict__ Wv5,
                                               const float* __restrict__ bv5,
                                               float* __restrict__ out) {
    __shared__ float red[NN][257];
    if (blockIdx.x < 176) {
        int idx4 = (blockIdx.x * 256 + threadIdx.x) * 4;  // 44*4096 elements
        int e = idx4 >> 12, f = idx4 & 4095;
        int se = SRC[e], de = DST[e];
        float4 ys = make_float4(0.f, 0.f, 0.f, 0.f);
        float4 yd = make_float4(0.f, 0.f, 0.f, 0.f);
#pragma unroll
        for (int kb = 0; kb < KB; ++kb) {
            float4 s = *(const float4*)(Ypa5 + kb * YPART + se * F + f);
            float4 d = *(const float4*)(Ypa5 + kb * YPART + de * F + f);
            ys.x += s.x; ys.y += s.y; ys.z += s.z; ys.w += s.w;
            yd.x += d.x; yd.y += d.y; yd.z += d.z; yd.w += d.w;
        }
        float4 bb = *(const float4*)(ba5 + f);
        float4 o;
        o.x = 0.5f * (ys.x + yd.x) + bb.x;
        o.y = 0.5f * (ys.y + yd.y) + bb.y;
        o.z = 0.5f * (ys.z + yd.z) + bb.z;
        o.w = 0.5f * (ys.w + yd.w) + bb.w;
        *(float4*)(out + idx4) = o;
    } else {
        // y[n] = dot(Av2[n], Wv5); h2[e] = 0.5*(y[src]+y[dst]) + bv5
        int t = threadIdx.x;
        float acc[NN];
#pragma unroll
        for (int m = 0; m < NN; ++m) acc[m] = 0.f;
        for (int f = t; f < F; f += 256) {
            float wv = Wv5[f];
#pragma unroll
            for (int m = 0; m < NN; ++m) acc[m] += Av2[m * F + f] * wv;
        }
#pragma unroll
        for (int m = 0; m < NN; ++m) red[m][t] = acc[m];
        __syncthreads();
        for (int s = 128; s > 0; s >>= 1) {
            if (t < s) {
#pragma unroll
                for (int m = 0; m < NN; ++m) red[m][t] += red[m][t + s];
            }
            __syncthreads();
        }
        if (t < NE) {
            float ys = red[SRC[t]][0], yd = red[DST[t]][0];
            out[H1SZ + t] = 0.5f * (ys + yd) + bv5[0];
        }
    }
}

extern "C" void kernel_launch(void* const* d_in, const int* in_sizes, int n_in,
                              void* d_out, int out_size, void* d_ws, size_t ws_size,
                              hipStream_t stream) {
    const float* x   = (const float*)d_in[0];
    const float* Wa1 = (const float*)d_in[3];
    const float* ba1 = (const float*)d_in[4];
    const float* Wa2 = (const float*)d_in[5];
    const float* ba2 = (const float*)d_in[6];
    const float* Wa5 = (const float*)d_in[7];
    const float* ba5 = (const float*)d_in[8];
    const float* Wv1 = (const float*)d_in[9];
    const float* bv1 = (const float*)d_in[10];
    const float* Wv2 = (const float*)d_in[11];
    const float* bv2 = (const float*)d_in[12];
    const float* Wv5 = (const float*)d_in[13];
    const float* bv5 = (const float*)d_in[14];
    float* out = (float*)d_out;

    float* ws  = (float*)d_ws;
    float* Ax  = ws;                   // 57344
    float* Aa  = ws + 57344;           // 57344
    float* Av  = ws + 114688;          // 57344
    float* Ypa = ws + 172032;          // KB*57344 = 917504
    float* Ypv = ws + 1089536;         // KB*57344 = 917504 (total ~8.03 MB)

    prep_x_k<<<16,   256, 0, stream>>>(x, Ax);
    gemm2_k <<<2048, 256, 0, stream>>>(Ax, Wa1, Ypa, Ax, Wv1, Ypv, 1024);
    prep2_k <<<32,   256, 0, stream>>>(Ypa, ba1, Aa, Ypv, bv1, Av);
    gemm2_k <<<2048, 256, 0, stream>>>(Aa, Wa2, Ypa, Av, Wv2, Ypv, 1024);
    prep2_k <<<32,   256, 0, stream>>>(Ypa, ba2, Aa, Ypv, bv2, Av);
    gemm2_k <<<1024, 256, 0, stream>>>(Aa, Wa5, Ypa, Aa, Wa5, Ypa, 1024);
    final_k <<<177,  256, 0, stream>>>(Ypa, ba5, Av, Wv5, bv5, out);
}